// Round 5
// baseline (876.390 us; speedup 1.0000x reference)
//
#include <hip/hip_runtime.h>
#include <hip/hip_bf16.h>

#define N_SAMP 100000
#define MPAD   100096   // 391*256
#define DIM    512
#define NCLS   100
#define NPROT  400
#define SLD    400      // S row stride (bf16 elements); 800 B rows, 16B-aligned
#define GCHUNK 16       // sample-chunks per class in gather
#define BM 256
#define BN 256
#define BK 64
#define MBC 391         // MPAD/BM
#define GEMM_GRID 782   // MBC*2

typedef unsigned short ushort_t;
typedef __attribute__((ext_vector_type(8))) short short8;
typedef __attribute__((ext_vector_type(8))) unsigned short ushort8;
typedef __attribute__((ext_vector_type(4))) float f32x4;

__device__ __forceinline__ float b2f(unsigned short u) {
    unsigned int x = ((unsigned int)u) << 16;
    return __builtin_bit_cast(float, x);
}
__device__ __forceinline__ unsigned short f2b(float f) {
    unsigned int x = __builtin_bit_cast(unsigned int, f);
    unsigned int lsb = (x >> 16) & 1u;
    x += 0x7fffu + lsb;
    return (unsigned short)(x >> 16);
}
__device__ __forceinline__ float wred(float v) {
    #pragma unroll
    for (int m = 1; m < 64; m <<= 1) v += __shfl_xor(v, m);
    return v;
}
__device__ __forceinline__ float wmax(float v) {
    #pragma unroll
    for (int m = 1; m < 64; m <<= 1) v = fmaxf(v, __shfl_xor(v, m));
    return v;
}
__device__ __forceinline__ void gload16(const void* g, void* l) {
    __builtin_amdgcn_global_load_lds((const __attribute__((address_space(1))) void*)g,
                                     (__attribute__((address_space(3))) void*)l, 16, 0, 0);
}

// ---------------- fused prep: cvt feat + cvt protos + label count ----------------
__global__ void k_prep(const float* __restrict__ f, const float* __restrict__ p,
                       const int* __restrict__ labels,
                       ushort_t* __restrict__ fb, ushort_t* __restrict__ pb,
                       int* __restrict__ counts) {
    __shared__ int h[NCLS];
    const int b = blockIdx.x;
    if (b < 25024) {
        size_t idx = ((size_t)b * 256 + threadIdx.x) * 8;
        ushort8 r = {0,0,0,0,0,0,0,0};
        if (idx < (size_t)N_SAMP * DIM) {
            f32x4 a = *(const f32x4*)(f + idx);
            f32x4 c = *(const f32x4*)(f + idx + 4);
            #pragma unroll
            for (int j = 0; j < 4; ++j) { r[j] = f2b(a[j]); r[4 + j] = f2b(c[j]); }
        }
        *(ushort8*)(fb + idx) = r;
    } else if (b < 25152) {
        size_t idx = ((size_t)(b - 25024) * 256 + threadIdx.x) * 8;
        ushort8 r = {0,0,0,0,0,0,0,0};
        if (idx < (size_t)NPROT * DIM) {
            f32x4 a = *(const f32x4*)(p + idx);
            f32x4 c = *(const f32x4*)(p + idx + 4);
            #pragma unroll
            for (int j = 0; j < 4; ++j) { r[j] = f2b(a[j]); r[4 + j] = f2b(c[j]); }
        }
        *(ushort8*)(pb + idx) = r;
    } else {
        for (int i = threadIdx.x; i < NCLS; i += 256) h[i] = 0;
        __syncthreads();
        const int step = 64 * 256;
        for (int n = (b - 25152) * 256 + threadIdx.x; n < N_SAMP; n += step)
            atomicAdd(&h[labels[n]], 1);
        __syncthreads();
        for (int i = threadIdx.x; i < NCLS; i += 256)
            if (h[i]) atomicAdd(&counts[i], h[i]);
    }
}

// ---------------- parallel prefix scan over 100 class counts ----------------
__global__ void k_scan(const int* __restrict__ counts, int* __restrict__ offsets,
                       int* __restrict__ cursor) {
    __shared__ int c[NCLS];
    const int t = threadIdx.x;
    if (t < NCLS) c[t] = counts[t];
    __syncthreads();
    if (t <= NCLS) {
        int acc = 0;
        for (int i = 0; i < t && i < NCLS; ++i) acc += c[i];
        offsets[t] = acc;
        if (t < NCLS) cursor[t] = acc;
    }
}

__global__ void k_scatter(const int* __restrict__ labels, int* __restrict__ cursor,
                          int* __restrict__ idxlist) {
    int n = blockIdx.x * blockDim.x + threadIdx.x;
    if (n < N_SAMP) {
        int p = atomicAdd(&cursor[labels[n]], 1);
        idxlist[p] = n;
    }
}

// ---------------- GEMM 256x256x64 + fused sink pass 1 ----------------
// C[MPAD,400(+pad)] = A[MPAD,512] @ B[512,512]^T, bf16; u1[k] += sum_rows exp(C*20)
// 512 thr = 8 waves (2 Mrows x 4 Ncols), wave-tile 128x64, acc[8][4] of 16x16.
// dbuf LDS + counted vmcnt; XOR-swizzle (linear LDS dest, pre-swizzled source, swizzled ds_read).
__global__ __launch_bounds__(512) void k_gemm(const ushort_t* __restrict__ A,
                                              const ushort_t* __restrict__ B,
                                              ushort_t* __restrict__ C,
                                              float* __restrict__ u1) {
    __shared__ ushort_t As[2][BM * BK];   // 64 KB
    __shared__ ushort_t Bs[2][BN * BK];   // 64 KB
    __shared__ float cs[256];
    // bijective XCD swizzle for nwg=782 (q=97, r=6)
    const int orig = blockIdx.x;
    const int xcd = orig & 7;
    const int loc = orig >> 3;
    const int wg = (xcd < 6 ? xcd * 98 : 588 + (xcd - 6) * 97) + loc;
    const int mb = wg >> 1, nb = wg & 1;
    const int m0 = mb * BM, n0 = nb * BN;
    const int tid = threadIdx.x;
    const int w = tid >> 6, lane = tid & 63;
    const int wr = w >> 2, wc = w & 3;
    const int l15 = lane & 15, l4 = lane >> 4;
    const int swr = l15 & 7;

    f32x4 acc[8][4] = {};

    // stage K-tile kt into buffer buf: LDS slot s (16B) <- global colblock (s&7)^(r&7), r=s>>3
    auto stage = [&](int buf, int kt) {
        const int k0 = kt * BK;
        #pragma unroll
        for (int it = 0; it < 4; ++it) {
            const int sb = it * 512 + w * 64;    // wave-uniform slot base
            const int s = sb + lane;
            const int r = s >> 3;
            const int c8 = ((s & 7) ^ (r & 7)) * 8;
            gload16(A + (size_t)(m0 + r) * DIM + k0 + c8, &As[buf][sb * 8]);
            gload16(B + (size_t)(n0 + r) * DIM + k0 + c8, &Bs[buf][sb * 8]);
        }
    };

    stage(0, 0);
    int cur = 0;
    for (int kt = 0; kt < 8; ++kt) {
        if (kt < 7) {
            stage(cur ^ 1, kt + 1);
            asm volatile("s_waitcnt vmcnt(8)" ::: "memory");   // cur's 8 loads done; next's in flight
        } else {
            asm volatile("s_waitcnt vmcnt(0)" ::: "memory");
        }
        __syncthreads();
        #pragma unroll
        for (int kk = 0; kk < 2; ++kk) {
            short8 af[8], bfr[4];
            #pragma unroll
            for (int mf = 0; mf < 8; ++mf) {
                const int row = wr * 128 + mf * 16 + l15;
                af[mf] = *(const short8*)(&As[cur][row * 64 + ((kk * 4 + l4) ^ swr) * 8]);
            }
            #pragma unroll
            for (int nf = 0; nf < 4; ++nf) {
                const int row = wc * 64 + nf * 16 + l15;
                bfr[nf] = *(const short8*)(&Bs[cur][row * 64 + ((kk * 4 + l4) ^ swr) * 8]);
            }
            #pragma unroll
            for (int mf = 0; mf < 8; ++mf)
                #pragma unroll
                for (int nf = 0; nf < 4; ++nf)
                    acc[mf][nf] = __builtin_amdgcn_mfma_f32_16x16x32_bf16(af[mf], bfr[nf], acc[mf][nf], 0, 0, 0);
        }
        __syncthreads();
        cur ^= 1;
    }
    // epilogue: store bf16 S + fused column exp-sums (sink pass 1)
    if (tid < 256) cs[tid] = 0.f;
    __syncthreads();
    #pragma unroll
    for (int nf = 0; nf < 4; ++nf) {
        const int col = n0 + wc * 64 + nf * 16 + l15;
        float csum = 0.f;
        if (col < NPROT) {
            #pragma unroll
            for (int mf = 0; mf < 8; ++mf)
                #pragma unroll
                for (int q = 0; q < 4; ++q) {
                    const int row = m0 + wr * 128 + mf * 16 + l4 * 4 + q;
                    unsigned short sb = f2b(acc[mf][nf][q]);
                    C[(size_t)row * SLD + col] = sb;
                    csum += __expf(b2f(sb) * 20.0f);
                }
        }
        csum += __shfl_xor(csum, 16);
        csum += __shfl_xor(csum, 32);
        if (l4 == 0 && col < NPROT)
            atomicAdd(&cs[wc * 64 + nf * 16 + l15], csum);
    }
    __syncthreads();
    if (tid < 256) {
        const int col = n0 + tid;
        if (col < NPROT) atomicAdd(&u1[col], cs[tid]);
    }
}

// ---------------- Sinkhorn pass: u_out[k] += E[n,k] / (B * sum_k E r_prev) ----------------
// WRITE_NEG: also write negv[n] = log(sum_k exp(10 s))
template<int WRITE_NEG>
__global__ __launch_bounds__(512) void k_sink(const ushort_t* __restrict__ S,
                                              const float* __restrict__ u_prev,
                                              float* __restrict__ u_out,
                                              float* __restrict__ negv) {
    __shared__ float part[8 * 512];
    const int tid = threadIdx.x;
    const int w = tid >> 6, lane = tid & 63;
    const bool lv = lane < 50;
    float rk[8];
    if (lv) {
        f32x4 u0 = *(const f32x4*)(u_prev + lane * 8);
        f32x4 u1 = *(const f32x4*)(u_prev + lane * 8 + 4);
        #pragma unroll
        for (int j = 0; j < 4; ++j) {
            rk[j] = 1.0f / (400.0f * u0[j]);
            rk[4 + j] = 1.0f / (400.0f * u1[j]);
        }
    } else {
        #pragma unroll
        for (int j = 0; j < 8; ++j) rk[j] = 0.0f;
    }
    float racc[8] = {0, 0, 0, 0, 0, 0, 0, 0};
    for (int row = blockIdx.x * 8 + w; row < N_SAMP; row += gridDim.x * 8) {
        short8 v = *(const short8*)(S + (size_t)row * SLD + lane * 8);
        float e[8];
        #pragma unroll
        for (int j = 0; j < 8; ++j)
            e[j] = lv ? __expf(b2f((unsigned short)v[j]) * 20.0f) : 0.0f;
        float t = 0.f;
        #pragma unroll
        for (int j = 0; j < 8; ++j) t += e[j] * rk[j];
        t = wred(t);
        float cn = 1.0f / ((float)N_SAMP * t);
        #pragma unroll
        for (int j = 0; j < 8; ++j) racc[j] += e[j] * cn;
        if (WRITE_NEG) {
            float sexp = 0.f;
            #pragma unroll
            for (int j = 0; j < 8; ++j) sexp += sqrtf(e[j]);   // exp(10 s)
            sexp = wred(sexp);
            if (lane == 0) negv[row] = logf(sexp);
        }
    }
    #pragma unroll
    for (int j = 0; j < 8; ++j) part[w * 512 + lane * 8 + j] = racc[j];
    __syncthreads();
    float s = 0.f;
    #pragma unroll
    for (int w2 = 0; w2 < 8; ++w2) s += part[w2 * 512 + tid];
    if (tid < NPROT) atomicAdd(&u_out[tid], s);
}

// ---------------- phase A finalize (4-col): w4[n,p] = E r3 at label protos, row-normalized ----------------
__global__ __launch_bounds__(256) void k_wprime(const ushort_t* __restrict__ S,
                                                const float* __restrict__ u3,
                                                const int* __restrict__ labels,
                                                float* __restrict__ w4) {
    const int n = blockIdx.x * 256 + threadIdx.x;
    if (n >= N_SAMP) return;
    const int lab = labels[n];
    const ushort_t* row = S + (size_t)n * SLD;
    float val[4], sum = 0.f;
    #pragma unroll
    for (int p = 0; p < 4; ++p) {
        const int k = lab + 100 * p;
        float e = __expf(b2f(row[k]) * 20.0f);
        float r = 1.0f / (400.0f * u3[k]);
        val[p] = e * r;
        sum += val[p];
    }
    f32x4 o;
    #pragma unroll
    for (int p = 0; p < 4; ++p) o[p] = val[p] / sum;
    *(f32x4*)(w4 + (size_t)n * 4) = o;
}

// ---------------- class-bucketed gather: plain partial stores (no atomics) ----------------
// pf[sc][(c+100p)*512 + d] ; pw[sc*400 + c+100p]
__global__ __launch_bounds__(128) void k_gather(const int* __restrict__ offsets,
                                                const int* __restrict__ idxlist,
                                                const float* __restrict__ w4,
                                                const ushort_t* __restrict__ fb,
                                                float* __restrict__ pf,
                                                float* __restrict__ pw) {
    const int c  = blockIdx.x / (4 * GCHUNK);
    const int rr = blockIdx.x % (4 * GCHUNK);
    const int dc = rr / GCHUNK;
    const int sc = rr % GCHUNK;
    const int d = dc * 128 + threadIdx.x;
    const int s = offsets[c], e = offsets[c + 1];
    const int cnt = e - s;
    const int per = (cnt + GCHUNK - 1) / GCHUNK;
    const int i0 = s + sc * per;
    const int i1 = min(e, i0 + per);
    if (i0 >= i1) return;
    float a0 = 0, a1 = 0, a2 = 0, a3 = 0, s0 = 0, s1 = 0, s2 = 0, s3 = 0;
    for (int i = i0; i < i1; ++i) {
        int n = idxlist[i];
        f32x4 wv = *(const f32x4*)(w4 + (size_t)n * 4);
        float f = b2f(fb[(size_t)n * DIM + d]);
        a0 += wv[0] * f; a1 += wv[1] * f; a2 += wv[2] * f; a3 += wv[3] * f;
        s0 += wv[0]; s1 += wv[1]; s2 += wv[2]; s3 += wv[3];
    }
    float* base = pf + (size_t)sc * (NPROT * DIM);
    base[(size_t)(c)       * DIM + d] = a0;
    base[(size_t)(c + 100) * DIM + d] = a1;
    base[(size_t)(c + 200) * DIM + d] = a2;
    base[(size_t)(c + 300) * DIM + d] = a3;
    if (dc == 0 && threadIdx.x == 0) {
        float* wb = pw + sc * NPROT;
        wb[c] = s0; wb[c + 100] = s1; wb[c + 200] = s2; wb[c + 300] = s3;
    }
}

// ---------------- EMA + renorm (fused 16-way partial reduction) ----------------
__global__ __launch_bounds__(64) void k_protonew(const float* __restrict__ protos,
                                                 const float* __restrict__ pf,
                                                 const float* __restrict__ pw,
                                                 float* __restrict__ pn,
                                                 ushort_t* __restrict__ pb) {
    const int k = blockIdx.x;
    const int lane = threadIdx.x;
    float cw = 0.f;
    #pragma unroll
    for (int sc = 0; sc < GCHUNK; ++sc) cw += pw[sc * NPROT + k];
    cw = fmaxf(cw, 1e-12f);
    float ufv[8] = {0, 0, 0, 0, 0, 0, 0, 0};
    for (int sc = 0; sc < GCHUNK; ++sc) {
        const float* base = pf + (size_t)sc * (NPROT * DIM) + (size_t)k * DIM + lane * 8;
        f32x4 a = *(const f32x4*)(base);
        f32x4 b = *(const f32x4*)(base + 4);
        #pragma unroll
        for (int j = 0; j < 4; ++j) { ufv[j] += a[j]; ufv[4 + j] += b[j]; }
    }
    float v[8]; float nn = 0.f;
    #pragma unroll
    for (int j = 0; j < 8; ++j) {
        int d = lane * 8 + j;
        float xx = 0.99f * protos[(size_t)k * DIM + d] + 0.01f * (ufv[j] / cw);
        v[j] = xx; nn += xx * xx;
    }
    nn = wred(nn);
    float inv = 1.0f / fmaxf(sqrtf(nn), 1e-12f);
    #pragma unroll
    for (int j = 0; j < 8; ++j) {
        int d = lane * 8 + j;
        float xx = v[j] * inv;
        pn[(size_t)k * DIM + d] = xx;
        pb[(size_t)k * DIM + d] = f2b(xx);
    }
}

// ---------------- proto-contrast ----------------
__global__ __launch_bounds__(256) void k_pcon(const float* __restrict__ pn, float* __restrict__ pacc) {
    __shared__ float pi[512];
    __shared__ float g[NPROT];
    __shared__ float rmx[4], rse[4], rsp[4];
    const int i = blockIdx.x;
    const int tid = threadIdx.x;
    const int w = tid >> 6, lane = tid & 63;
    for (int d = tid; d < 512; d += 256) pi[d] = pn[(size_t)i * DIM + d];
    __syncthreads();
    for (int j = w; j < NPROT; j += 4) {
        const float* pj = pn + (size_t)j * DIM;
        f32x4 p0 = *(const f32x4*)(pj + lane * 8);
        f32x4 p1 = *(const f32x4*)(pj + lane * 8 + 4);
        float dot = 0.f;
        #pragma unroll
        for (int jj = 0; jj < 4; ++jj) {
            dot += pi[lane * 8 + jj] * p0[jj];
            dot += pi[lane * 8 + 4 + jj] * p1[jj];
        }
        dot = wred(dot);
        if (lane == 0) g[j] = dot * 2.0f;
    }
    __syncthreads();
    float mx = -1e30f;
    for (int j = tid; j < NPROT; j += 256) mx = fmaxf(mx, g[j]);
    mx = wmax(mx);
    if (lane == 0) rmx[w] = mx;
    __syncthreads();
    mx = fmaxf(fmaxf(rmx[0], rmx[1]), fmaxf(rmx[2], rmx[3]));
    const int ci = i % 100;
    float se = 0.f, sp = 0.f;
    for (int j = tid; j < NPROT; j += 256) {
        if (j == i) continue;
        float lg = g[j] - mx;
        se += __expf(lg);
        if (j % 100 == ci) sp += lg;
    }
    se = wred(se); sp = wred(sp);
    if (lane == 0) { rse[w] = se; rsp[w] = sp; }
    __syncthreads();
    if (tid == 0) {
        float SE = rse[0] + rse[1] + rse[2] + rse[3];
        float SP = rsp[0] + rsp[1] + rsp[2] + rsp[3];
        atomicAdd(pacc, SP * (1.0f / 3.0f) - logf(SE));
    }
}

// ---------------- phase B finalize (4-col + precomputed neg) ----------------
__global__ __launch_bounds__(256) void k_final(const ushort_t* __restrict__ S,
                                               const float* __restrict__ u3,
                                               const int* __restrict__ labels,
                                               const float* __restrict__ negv,
                                               const float* __restrict__ pacc,
                                               float* __restrict__ out) {
    const int n = blockIdx.x * 256 + threadIdx.x;
    if (n >= N_SAMP) return;
    const int lab = labels[n];
    const ushort_t* row = S + (size_t)n * SLD;
    float sw = 0.f, swl = 0.f;
    #pragma unroll
    for (int p = 0; p < 4; ++p) {
        const int k = lab + 100 * p;
        float s = b2f(row[k]);
        float e = __expf(s * 20.0f);
        float r = 1.0f / (400.0f * u3[k]);
        float v = e * r;
        sw += v;
        swl += v * (s * 10.0f);
    }
    out[n] = (negv[n] - swl / sw) - pacc[0] * (1.0f / 400.0f);
}

extern "C" void kernel_launch(void* const* d_in, const int* in_sizes, int n_in,
                              void* d_out, int out_size, void* d_ws, size_t ws_size,
                              hipStream_t stream) {
    const float* features = (const float*)d_in[0];
    const float* protos   = (const float*)d_in[1];
    const int*   labels   = (const int*)d_in[2];
    float* out = (float*)d_out;

    char* ws = (char*)d_ws;
    size_t off = 0;
    auto alloc = [&](size_t bytes) -> char* {
        char* p = ws + off;
        off += (bytes + 255) & ~(size_t)255;
        return p;
    };
    ushort_t* fbf16 = (ushort_t*)alloc((size_t)MPAD * DIM * 2);
    ushort_t* Sbuf  = (ushort_t*)alloc((size_t)MPAD * SLD * 2);
    ushort_t* pbf16 = (ushort_t*)alloc((size_t)DIM * DIM * 2);
    float* w4   = (float*)alloc((size_t)N_SAMP * 4 * 4);
    float* pnf  = (float*)alloc((size_t)NPROT * DIM * 4);
    float* negv = (float*)alloc((size_t)N_SAMP * 4);
    // ---- zeroed region: zreg + pf + pw, contiguous ----
    float* zreg = (float*)alloc(16384);
    float* pf   = (float*)alloc((size_t)GCHUNK * NPROT * DIM * 4);  // 13.1 MB
    float* pw   = (float*)alloc((size_t)GCHUNK * NPROT * 4);        // 25.6 KB
    float* uA1 = zreg;          float* uA2 = zreg + 512;  float* uA3 = zreg + 1024;
    float* uB1 = zreg + 1536;   float* uB2 = zreg + 2048; float* uB3 = zreg + 2560;
    float* pacc = zreg + 3072;
    int* counts = (int*)(zreg + 3080);
    int* offsets = (int*)alloc(101 * 4);
    int* cursor  = (int*)alloc(100 * 4);
    int* idxlist = (int*)alloc((size_t)N_SAMP * 4);
    if (off > ws_size) return;

    const size_t zbytes = 16384 + (size_t)GCHUNK * NPROT * DIM * 4 + (size_t)GCHUNK * NPROT * 4;
    hipMemsetAsync(zreg, 0, zbytes, stream);

    k_prep<<<25216, 256, 0, stream>>>(features, protos, labels, fbf16, pbf16, counts);
    k_scan<<<1, 128, 0, stream>>>(counts, offsets, cursor);
    k_scatter<<<(N_SAMP + 255) / 256, 256, 0, stream>>>(labels, cursor, idxlist);

    // ---- phase A ----
    k_gemm<<<GEMM_GRID, 512, 0, stream>>>(fbf16, pbf16, Sbuf, uA1);
    k_sink<0><<<512, 512, 0, stream>>>(Sbuf, uA1, uA2, nullptr);
    k_sink<0><<<512, 512, 0, stream>>>(Sbuf, uA2, uA3, nullptr);
    k_wprime<<<(N_SAMP + 255) / 256, 256, 0, stream>>>(Sbuf, uA3, labels, w4);
    k_gather<<<NCLS * 4 * GCHUNK, 128, 0, stream>>>(offsets, idxlist, w4, fbf16, pf, pw);
    k_protonew<<<400, 64, 0, stream>>>(protos, pf, pw, pnf, pbf16);
    k_pcon<<<400, 256, 0, stream>>>(pnf, pacc);

    // ---- phase B ----
    k_gemm<<<GEMM_GRID, 512, 0, stream>>>(fbf16, pbf16, Sbuf, uB1);
    k_sink<0><<<512, 512, 0, stream>>>(Sbuf, uB1, uB2, nullptr);
    k_sink<1><<<512, 512, 0, stream>>>(Sbuf, uB2, uB3, negv);
    k_final<<<(N_SAMP + 255) / 256, 256, 0, stream>>>(Sbuf, uB3, labels, negv, pacc, out);
}